// Round 4
// baseline (146.102 us; speedup 1.0000x reference)
//
#include <hip/hip_runtime.h>
#include <math.h>

static constexpr int TB = 64;   // batch
static constexpr int LL = 32;   // labels
static constexpr int SS = 256;  // max target length
static constexpr int STRIDE_T = TB * LL;  // floats per time step (2048)

// ---- workspace layout (floats per batch) --------------------------------
static constexpr int OF_FWD  = 0;                 // 33: alpha[32] + K
static constexpr int OF_BWD  = 33;                // 33: v[32] + K
static constexpr int OF_MC   = 66;                // 32 cols x 33 (mid matrix)
static constexpr int OF_FACF = 2178;              // 256 vals + 64 scales
static constexpr int OF_FACB = 2498;              // 256 vals + 64 scales
static constexpr int WSB     = 2818;              // per-batch stride

#define LN2F 0.69314718055994530942f
#define NEGF (-1e30f)

// raw barrier: waits LDS only (keeps global-load prefetch in flight)
#define BARX() { asm volatile("s_waitcnt lgkmcnt(0)" ::: "memory"); \
                 __builtin_amdgcn_s_barrier(); \
                 asm volatile("" ::: "memory"); }

// ---- DPP / cross-lane helpers ------------------------------------------
template<int CTL>
__device__ __forceinline__ float dpp_f(float x, float oldv) {
  return __int_as_float(__builtin_amdgcn_update_dpp(
      __float_as_int(oldv), __float_as_int(x), CTL, 0xF, 0xF, false));
}
template<int M>
__device__ __forceinline__ int rot_i(int x) {
  return __builtin_amdgcn_update_dpp(0, x, 0x120 + M, 0xF, 0xF, false); // row_ror:M
}

typedef unsigned uint2v __attribute__((ext_vector_type(2)));
__device__ __forceinline__ float xsum16(float x) {  // x[l] + x[l^16]
  uint2v r = __builtin_amdgcn_permlane16_swap(__float_as_uint(x), __float_as_uint(x), false, false);
  return __uint_as_float(r.x) + __uint_as_float(r.y);
}
__device__ __forceinline__ float xsum32(float x) {  // x[l] + x[l^32]
  uint2v r = __builtin_amdgcn_permlane32_swap(__float_as_uint(x), __float_as_uint(x), false, false);
  return __uint_as_float(r.x) + __uint_as_float(r.y);
}
__device__ __forceinline__ float bperm(int addr, float src) {  // pull lane addr>>2
  return __int_as_float(__builtin_amdgcn_ds_bpermute(addr, __float_as_int(src)));
}

// Self-calibrating coefficient load (rot_i matches row_ror:M exactly)
template<int M>
struct Calib {
  __device__ static __forceinline__ void run(const float* trans, int lam, int i, float* Ec) {
    Ec[M] = __expf(trans[i * LL + rot_i<M>(lam)]);
    Calib<M + 1>::run(trans, lam, i, Ec);
  }
};
template<> struct Calib<16> {
  __device__ static __forceinline__ void run(const float*, int, int, float*) {}
};
// Transposed variant: coefficient trans[rot(lam)][i]  (M^T matvec)
template<int M>
struct CalibT {
  __device__ static __forceinline__ void run(const float* trans, int lam, int i, float* Ec) {
    Ec[M] = __expf(trans[rot_i<M>(lam) * LL + i]);
    CalibT<M + 1>::run(trans, lam, i, Ec);
  }
};
template<> struct CalibT<16> {
  __device__ static __forceinline__ void run(const float*, int, int, float*) {}
};

// ---- fused rotate-multiply asm (1 instr per term) -----------------------
#define ROT_MUL(DST, SRC, COEF, ROT) \
  asm("v_mul_f32_dpp %0, %1, %2 row_ror:" #ROT " row_mask:0xf bank_mask:0xf" \
      : "=v"(DST) : "v"(SRC), "v"(COEF))
#define ROT_FMAC(ACC, SRC, COEF, ROT) \
  asm("v_fmac_f32_dpp %0, %1, %2 row_ror:" #ROT " row_mask:0xf bank_mask:0xf" \
      : "+v"(ACC) : "v"(SRC), "v"(COEF))

// matvec over 16-lane rows: 8 indep chains of depth 2, then 3-level tree
#define STEP16(EC) { \
  float a0 = EC[0] * A, a1, a2, a3, a4, a5, a6, a7; \
  ROT_MUL(a1, A, EC[1], 1); ROT_MUL(a2, A, EC[2], 2); ROT_MUL(a3, A, EC[3], 3); \
  ROT_MUL(a4, A, EC[4], 4); ROT_MUL(a5, A, EC[5], 5); ROT_MUL(a6, A, EC[6], 6); \
  ROT_MUL(a7, A, EC[7], 7); \
  ROT_FMAC(a0, A, EC[8], 8);   ROT_FMAC(a1, A, EC[9], 9); \
  ROT_FMAC(a2, A, EC[10], 10); ROT_FMAC(a3, A, EC[11], 11); \
  ROT_FMAC(a4, A, EC[12], 12); ROT_FMAC(a5, A, EC[13], 13); \
  ROT_FMAC(a6, A, EC[14], 14); ROT_FMAC(a7, A, EC[15], 15); \
  part = ((a0 + a1) + (a2 + a3)) + ((a4 + a5) + (a6 + a7)); }

// ======================= FCC chain ======================================

#define FCC_RENORM() { \
  unsigned uu = (unsigned)__builtin_amdgcn_readfirstlane((int)__float_as_uint(A)); \
  int ex = (int)((uu >> 23) & 255) - 127; \
  A = ldexpf(A, -ex); Kt += ex; }

#define FCC_STEP_E(Q) { float part; STEP16(Ec1); A = eb[Q] * xsum16(part); }
#define FCC_STEP_O(Q) { float part; STEP16(Ec2); A = eb[Q] * xsum32(part); }

#define FCC_CONSUME16(PB) { \
  float eb[16]; \
  _Pragma("unroll") for (int q = 0; q < 16; ++q) eb[q] = sE[PB][q][(q & 1) ? lam1 : lam2]; \
  FCC_STEP_E(0); FCC_STEP_O(1); FCC_STEP_E(2); FCC_STEP_O(3); \
  FCC_STEP_E(4); FCC_STEP_O(5); FCC_STEP_E(6); FCC_STEP_O(7); \
  FCC_RENORM(); \
  FCC_STEP_E(8); FCC_STEP_O(9); FCC_STEP_E(10); FCC_STEP_O(11); \
  FCC_STEP_E(12); FCC_STEP_O(13); FCC_STEP_E(14); FCC_STEP_O(15); \
  FCC_RENORM(); }

#define FCC_TAIL16(PB, CNT) { \
  float eb[16]; \
  _Pragma("unroll") for (int q = 0; q < 16; ++q) eb[q] = sE[PB][q][(q & 1) ? lam1 : lam2]; \
  _Pragma("unroll") for (int q = 0; q < 16; ++q) { \
    if (q >= (CNT)) break; \
    if ((q & 1) == 0) { float part; STEP16(Ec1); A = eb[q] * xsum16(part); } \
    else              { float part; STEP16(Ec2); A = eb[q] * xsum32(part); } \
    if (q == 7) { FCC_RENORM(); } } }

// backward (transpose): consumes rows 15..0; emission multiplies BEFORE matvec
#define FCC_BSTEP_A(Q) { A *= eb[Q]; float part; STEP16(E1T); A = xsum16(part); }
#define FCC_BSTEP_B(Q) { A *= eb[Q]; float part; STEP16(E2T); A = xsum32(part); }

#define FCC_BWDCON16(PB) { \
  float eb[16]; \
  _Pragma("unroll") for (int q = 0; q < 16; ++q) eb[q] = sE[PB][q][(q & 1) ? lam1 : lam2]; \
  FCC_BSTEP_A(15); FCC_BSTEP_B(14); FCC_BSTEP_A(13); FCC_BSTEP_B(12); \
  FCC_BSTEP_A(11); FCC_BSTEP_B(10); FCC_BSTEP_A(9);  FCC_BSTEP_B(8); \
  FCC_RENORM(); \
  FCC_BSTEP_A(7);  FCC_BSTEP_B(6);  FCC_BSTEP_A(5);  FCC_BSTEP_B(4); \
  FCC_BSTEP_A(3);  FCC_BSTEP_B(2);  FCC_BSTEP_A(1);  FCC_BSTEP_B(0); \
  FCC_RENORM(); }

// ======================= FAC chain ======================================

#define FAC_STEP(E0, E1, E2, E3) { \
  float ap = dpp_f<0x138>(A3, 0.f); /* wave_shr:1 */ \
  float n0 = (E0) * fmaf(MV0b,  ap, ST[0] * A0); \
  float n1 = (E1) * fmaf(MVl[1], A0, ST[1] * A1); \
  float n2 = (E2) * fmaf(MVl[2], A1, ST[2] * A2); \
  float n3 = (E3) * fmaf(MVl[3], A2, ST[3] * A3); \
  A0 = n0; A1 = n1; A2 = n2; A3 = n3; }

#define FAC_BOUNDARY() { \
  float maxA = fmaxf(fmaxf(A0, A1), fmaxf(A2, A3)); \
  if (maxA > 0.f) { \
    int ex = (int)((__float_as_uint(maxA) >> 23) & 255) - 127; \
    A0 = ldexpf(A0, -ex); A1 = ldexpf(A1, -ex); \
    A2 = ldexpf(A2, -ex); A3 = ldexpf(A3, -ex); \
    m += (float)ex; \
  } \
  float mp = dpp_f<0x138>(m, NEGF); m = (m == NEGF) ? mp : m; \
  mp = dpp_f<0x138>(m, NEGF);       m = (m == NEGF) ? mp : m; \
  mp = dpp_f<0x138>(m, NEGF); \
  float dlt = fminf(mp - m, 50.0f); \
  float Sin = exp2f(dlt); \
  MV0b = MVl[0] * Sin; }

#define FACF_CON16(PB) { \
  float4 Er[16]; \
  _Pragma("unroll") for (int r = 0; r < 16; ++r) Er[r] = sF[PB][r][l]; \
  _Pragma("unroll") for (int r = 0; r < 8; ++r) \
    FAC_STEP(Er[r].x, Er[r].y, Er[r].z, Er[r].w); \
  FAC_BOUNDARY(); \
  _Pragma("unroll") for (int r = 8; r < 16; ++r) \
    FAC_STEP(Er[r].x, Er[r].y, Er[r].z, Er[r].w); \
  FAC_BOUNDARY(); }

#define FACF_TAIL16(PB, CNT) { \
  float4 Er[16]; \
  _Pragma("unroll") for (int r = 0; r < 16; ++r) Er[r] = sF[PB][r][l]; \
  _Pragma("unroll") for (int r = 0; r < 16; ++r) { \
    if (r >= (CNT)) break; \
    FAC_STEP(Er[r].x, Er[r].y, Er[r].z, Er[r].w); \
    if (r == 7) { FAC_BOUNDARY(); } } }

#define FACB_BOUNDARY() { \
  float maxA = fmaxf(fmaxf(A0, A1), fmaxf(A2, A3)); \
  if (maxA > 0.f) { \
    int ex = (int)((__float_as_uint(maxA) >> 23) & 255) - 127; \
    A0 = ldexpf(A0, -ex); A1 = ldexpf(A1, -ex); \
    A2 = ldexpf(A2, -ex); A3 = ldexpf(A3, -ex); \
    m += (float)ex; \
  } \
  float mp = dpp_f<0x130>(m, NEGF); m = (m == NEGF) ? mp : m; \
  mp = dpp_f<0x130>(m, NEGF);       m = (m == NEGF) ? mp : m; \
  mp = dpp_f<0x130>(m, NEGF); \
  float dlt = fminf(mp - m, 50.0f); \
  MVn3b = MVn[3] * exp2f(dlt); }

#define FACB_STEP(Q) { \
    float en3 = dpp_f<0x130>(Er[Q].x, 0.f); /* wave_shl:1 */ \
    float an  = dpp_f<0x130>(A0, 0.f); \
    float n0 = fmaf(Er[Q].y * MVn[0], A1, Er[Q].x * ST[0] * A0); \
    float n1 = fmaf(Er[Q].z * MVn[1], A2, Er[Q].y * ST[1] * A1); \
    float n2 = fmaf(Er[Q].w * MVn[2], A3, Er[Q].z * ST[2] * A2); \
    float n3 = fmaf(en3 * MVn3b,      an, Er[Q].w * ST[3] * A3); \
    A0 = n0; A1 = n1; A2 = n2; A3 = n3; }

#define FACB_CON16(PB) { \
  float4 Er[16]; \
  _Pragma("unroll") for (int r = 0; r < 16; ++r) Er[r] = sF[PB][r][l]; \
  FACB_STEP(15); FACB_STEP(14); FACB_STEP(13); FACB_STEP(12); \
  FACB_STEP(11); FACB_STEP(10); FACB_STEP(9);  FACB_STEP(8); \
  FACB_BOUNDARY(); \
  FACB_STEP(7);  FACB_STEP(6);  FACB_STEP(5);  FACB_STEP(4); \
  FACB_STEP(3);  FACB_STEP(2);  FACB_STEP(1);  FACB_STEP(0); \
  FACB_BOUNDARY(); }

// ======================= staging loads ==================================

// fwd load: phase Q rows start at T0 + 16Q; pair K = rows 2K,2K+1 (via rowoff)
#define HLDF(Q, K, T0) ({ \
  int tt_ = (T0) + 16 * (Q) + 2 * (K) + rowoff; \
  tt_ = tt_ > lenm1 ? lenm1 : tt_; \
  gpl[(size_t)tt_ * STRIDE_T]; })
// bwd load: phase Q rows are [lenm1-16Q-15, lenm1-16Q]
#define HLDB(Q, K) ({ \
  int tt_ = lenm1 - 16 * (Q) - 15 + 2 * (K) + rowoff; \
  tt_ = tt_ < 0 ? 0 : (tt_ > lenm1 ? lenm1 : tt_); \
  gpl[(size_t)tt_ * STRIDE_T]; })
#define HLD2(Q, K) ( isfwd ? HLDF(Q, K, 1) : HLDB(Q, K) )

#define PROD_FCC(PB, KK, RV) { sE[PB][2 * (KK) + rowoff][lam1] = __expf(RV); }

#define PROD_FAC(PB, KK, RV) { \
  float e_ = __expf(RV); \
  float4 E0_, E1_; \
  E0_.x = bperm(adA[0], e_); E0_.y = bperm(adA[1], e_); \
  E0_.z = bperm(adA[2], e_); E0_.w = bperm(adA[3], e_); \
  E1_.x = bperm(adB[0], e_); E1_.y = bperm(adB[1], e_); \
  E1_.z = bperm(adB[2], e_); E1_.w = bperm(adB[3], e_); \
  sF[PB][2 * (KK)][l]     = E0_; \
  sF[PB][2 * (KK) + 1][l] = E1_; }

#define PRODUCE(PB, VA, VB) { \
  if (fac) { PROD_FAC(PB, kh, VA); PROD_FAC(PB, kh + 1, VB); } \
  else     { PROD_FCC(PB, kh, VA); PROD_FCC(PB, kh + 1, VB); } }

// ======================= main kernel ====================================
// grid: [0,256)   = FCC mid-chunk basis blocks (8 column-waves each)
//       [256,512) = role blocks: 1 chain wave + 4 helpers + 3 barrier dummies

extern "C" __global__ __launch_bounds__(512, 1)
void asg_main(const float* __restrict__ trans, const float* __restrict__ inputs,
              const int* __restrict__ targets, const int* __restrict__ ilen,
              const int* __restrict__ tlen, float* __restrict__ ws) {
  const int tid = (int)threadIdx.x;
  const int w = tid >> 6;
  const int l = tid & 63;
  const int lam1 = l & 31;
  const int lam2 = (l & 15) | ((l >> 5) << 4);
  const int rowoff = l >> 5;
  const int bid = (int)blockIdx.x;

  __shared__ float  sE[2][16][32];   // FCC emission exp staging (4 KB)
  __shared__ float4 sF[2][16][64];   // FAC per-lane E staging  (32 KB)

  if (bid < 4 * TB) {
    // ================= FCC basis blocks: P_mid columns ==================
    // same-batch blocks share an XCD (L2 reuse of staged rows)
    const int xcd = bid & 7, r = bid >> 3;
    const int b = xcd + 8 * (r >> 2);
    const int cb = r & 3;                  // column group: cols 8*cb..8*cb+7
    const int len = ilen[b];
    const int lenm1 = len - 1;
    const int Lsteps = lenm1;
    const int third = (Lsteps / 3) & ~15;
    const int nf0 = Lsteps - 2 * third;    // fwd chain length
    const int nph = third >> 4;            // basis phases (third mult of 16)
    const int t0 = nf0 + 1;

    const float* gpl = inputs + (size_t)b * LL + lam1;
    float* P = ws + (size_t)b * WSB;

    float Ec1[16], Ec2[16];
    Ec1[0] = __expf(trans[lam2 * LL + lam1]);
    Ec2[0] = __expf(trans[lam1 * LL + lam2]);
    Calib<1>::run(trans, lam1, lam2, Ec1);
    Calib<1>::run(trans, lam2, lam1, Ec2);

    const int col = 8 * cb + w;
    float A = (lam1 == col) ? 1.f : 0.f;
    int Kt = 0;

    // fused producer/consumer: each wave stages pair K=w (rows 2w, 2w+1)
    float R1 = HLDF(0, w, t0), R2 = HLDF(1, w, t0), R3 = HLDF(2, w, t0);
    PROD_FCC(0, w, R1);
    R1 = R2; R2 = R3; R3 = HLDF(3, w, t0);

    for (int p = 0; p < nph; p += 2) {
      BARX();
      if (p + 1 < nph) { float N = HLDF(p + 4, w, t0); PROD_FCC(1, w, R1);
                         R1 = R2; R2 = R3; R3 = N; }
      FCC_CONSUME16(0);
      BARX();
      if (p + 2 < nph) { float N = HLDF(p + 5, w, t0); PROD_FCC(0, w, R1);
                         R1 = R2; R2 = R3; R3 = N; }
      if (p + 1 < nph) { FCC_CONSUME16(1); }
    }
    // third even -> lam1 layout
    if (l < 32) P[OF_MC + col * 33 + lam1] = A;
    if (l == 0) P[OF_MC + col * 33 + 32] = (float)Kt;
    return;
  }

  // ================= role blocks ======================================
  const int rid  = bid - 4 * TB;
  const int role = rid >> 6;  // 0 FCCfwd, 1 FCCbwd, 2 FACfwd, 3 FACbwd
  const int b    = rid & 63;

  const int len = ilen[b];
  const int lenm1 = len - 1;
  const int Lsteps = lenm1;
  const int third = (Lsteps / 3) & ~15;   // FCC bwd & basis length
  const int nf0 = Lsteps - 2 * third;     // FCC fwd length (tail ok)
  const int nbf = (Lsteps / 2) & ~15;     // FAC bwd length
  const int nff = Lsteps - nbf;           // FAC fwd length (tail ok)
  const bool isfwd = (role == 0) || (role == 2);
  const int nsteps = (role == 0) ? nf0 : (role == 1) ? third
                    : (role == 2) ? nff : nbf;
  const int nph = (nsteps + 15) >> 4;

  const float* gpl = inputs + (size_t)b * LL + lam1;
  float* P = ws + (size_t)b * WSB;

  if (w == 0) {
    // ================= chain wave ======================================
    __builtin_amdgcn_s_setprio(1);

    if (role == 0) {
      // ---- FCC forward vector scan ----
      float Ec1[16], Ec2[16];
      Ec1[0] = __expf(trans[lam2 * LL + lam1]);
      Ec2[0] = __expf(trans[lam1 * LL + lam2]);
      Calib<1>::run(trans, lam1, lam2, Ec1);
      Calib<1>::run(trans, lam2, lam1, Ec2);
      float A = __expf(inputs[(size_t)b * LL + lam1]);
      int Kt = 0;
      for (int p = 0; p < nph; p += 2) {
        BARX();
        { const int rem = nsteps - 16 * p;
          if (rem >= 16) { FCC_CONSUME16(0); } else { FCC_TAIL16(0, rem); } }
        BARX();
        if (p + 1 < nph) {
          const int rem = nsteps - 16 * (p + 1);
          if (rem >= 16) { FCC_CONSUME16(1); } else { FCC_TAIL16(1, rem); }
        }
      }
      const int par = nsteps & 1;
      const int idx = par ? lam2 : lam1;
      const bool wr = par ? ((l & 16) == 0) : (l < 32);
      if (wr) P[OF_FWD + idx] = A;
      if (l == 0) P[OF_FWD + 32] = (float)Kt;

    } else if (role == 1) {
      // ---- FCC backward (transpose) vector scan ----
      float E1T[16], E2T[16];
      E1T[0] = __expf(trans[lam1 * LL + lam2]);
      E2T[0] = __expf(trans[lam2 * LL + lam1]);
      CalibT<1>::run(trans, lam1, lam2, E1T);
      CalibT<1>::run(trans, lam2, lam1, E2T);
      float A = 1.f;
      int Kt = 0;
      for (int p = 0; p < nph; p += 2) {
        BARX();
        FCC_BWDCON16(0);
        BARX();
        if (p + 1 < nph) { FCC_BWDCON16(1); }
      }
      if (l < 32) P[OF_BWD + lam1] = A;        // third even -> lam1 layout
      if (l == 0) P[OF_BWD + 32] = (float)Kt;

    } else if (role == 2) {
      // ---- FAC forward half ----
      int tg[4];
      #pragma unroll
      for (int q = 0; q < 4; ++q) tg[q] = targets[b * SS + 4 * l + q];
      float ST[4], MVl[4];
      #pragma unroll
      for (int q = 0; q < 4; ++q) ST[q] = __expf(trans[tg[q] * LL + tg[q]]);
      MVl[0] = (l == 0) ? 0.f : __expf(trans[tg[0] * LL + targets[b * SS + 4 * l - 1]]);
      #pragma unroll
      for (int q = 1; q < 4; ++q) MVl[q] = __expf(trans[tg[q] * LL + tg[q - 1]]);

      float A0 = (l == 0) ? __expf(inputs[(size_t)b * LL + tg[0]]) : 0.f;
      float A1 = 0.f, A2 = 0.f, A3 = 0.f;
      float m  = (l == 0) ? 0.f : NEGF;
      float MV0b;
      FAC_BOUNDARY();

      for (int p = 0; p < nph; p += 2) {
        BARX();
        { const int rem = nsteps - 16 * p;
          if (rem >= 16) { FACF_CON16(0); } else { FACF_TAIL16(0, rem); } }
        BARX();
        if (p + 1 < nph) {
          const int rem = nsteps - 16 * (p + 1);
          if (rem >= 16) { FACF_CON16(1); } else { FACF_TAIL16(1, rem); }
        }
      }
      P[OF_FACF + 4 * l + 0] = A0;
      P[OF_FACF + 4 * l + 1] = A1;
      P[OF_FACF + 4 * l + 2] = A2;
      P[OF_FACF + 4 * l + 3] = A3;
      P[OF_FACF + 256 + l]   = m;

    } else {
      // ---- FAC backward half (beta) ----
      const int tl = tlen[b];
      const int fs = tl - 1;
      int tg[4];
      #pragma unroll
      for (int q = 0; q < 4; ++q) tg[q] = targets[b * SS + 4 * l + q];
      float ST[4], MVn[4];
      #pragma unroll
      for (int q = 0; q < 4; ++q) ST[q] = __expf(trans[tg[q] * LL + tg[q]]);
      MVn[0] = __expf(trans[tg[1] * LL + tg[0]]);
      MVn[1] = __expf(trans[tg[2] * LL + tg[1]]);
      MVn[2] = __expf(trans[tg[3] * LL + tg[2]]);
      int tgn3 = (l < 63) ? targets[b * SS + 4 * l + 4] : 0;
      MVn[3] = (l < 63) ? __expf(trans[tgn3 * LL + tg[3]]) : 0.f;

      float A0 = (4 * l + 0 == fs) ? 1.f : 0.f;
      float A1 = (4 * l + 1 == fs) ? 1.f : 0.f;
      float A2 = (4 * l + 2 == fs) ? 1.f : 0.f;
      float A3 = (4 * l + 3 == fs) ? 1.f : 0.f;
      float m  = (l == (fs >> 2)) ? 0.f : NEGF;
      float MVn3b;
      FACB_BOUNDARY();

      for (int p = 0; p < nph; p += 2) {
        BARX();
        FACB_CON16(0);
        BARX();
        if (p + 1 < nph) { FACB_CON16(1); }
      }
      P[OF_FACB + 4 * l + 0] = A0;
      P[OF_FACB + 4 * l + 1] = A1;
      P[OF_FACB + 4 * l + 2] = A2;
      P[OF_FACB + 4 * l + 3] = A3;
      P[OF_FACB + 256 + l]   = m;
    }

  } else if (w <= 4) {
    // ================= helper waves (emission producers) ================
    const int kh = 2 * (w - 1);          // pair indices kh, kh+1
    const bool fac = (role >= 2);
    int adA[4] = {0, 0, 0, 0}, adB[4] = {0, 0, 0, 0};
    if (fac) {
      #pragma unroll
      for (int j = 0; j < 4; ++j) {
        int tg = targets[b * SS + 4 * l + j];
        adA[j] = tg * 4; adB[j] = adA[j] + 128;
      }
    }
    // 3-stage register prefetch queue
    float R1a = HLD2(0, kh), R1b = HLD2(0, kh + 1);
    float R2a = HLD2(1, kh), R2b = HLD2(1, kh + 1);
    float R3a = HLD2(2, kh), R3b = HLD2(2, kh + 1);
    PRODUCE(0, R1a, R1b);
    R1a = R2a; R1b = R2b; R2a = R3a; R2b = R3b;
    R3a = HLD2(3, kh); R3b = HLD2(3, kh + 1);

    for (int p = 0; p < nph; p += 2) {
      BARX();
      if (p + 1 < nph) {
        float Na = HLD2(p + 4, kh), Nb = HLD2(p + 4, kh + 1);
        PRODUCE(1, R1a, R1b);
        R1a = R2a; R1b = R2b; R2a = R3a; R2b = R3b; R3a = Na; R3b = Nb;
      }
      BARX();
      if (p + 2 < nph) {
        float Na = HLD2(p + 5, kh), Nb = HLD2(p + 5, kh + 1);
        PRODUCE(0, R1a, R1b);
        R1a = R2a; R1b = R2b; R2a = R3a; R2b = R3b; R3a = Na; R3b = Nb;
      }
    }

  } else {
    // ================= dummy waves: barrier participation only ==========
    const int I = (nph + 1) >> 1;
    for (int i = 0; i < I; ++i) { BARX(); BARX(); }
  }
}

// ======================= combine ========================================

extern "C" __global__ __launch_bounds__(1024)
void asg_combine(const float* __restrict__ ws, float* __restrict__ out) {
  __shared__ float sd[TB];
  const int tid = (int)threadIdx.x;
  const int w = tid >> 6, l = tid & 63;

  for (int k = 0; k < 4; ++k) {
    const int b = w * 4 + k;
    const float* P = ws + (size_t)b * WSB;

    // ---- FCC: score = v^T * P_mid * alpha (with 2^K bookkeeping) ----
    float al  = (l < 32) ? P[OF_FWD + l] : 0.f;
    float Kacc = P[OF_FWD + 32] + P[OF_BWD + 32];

    float KA = (l < 32) ? P[OF_MC + 33 * l + 32] : -3.0e38f;
    float Km = KA;
    #pragma unroll
    for (int s = 1; s < 64; s <<= 1) Km = fmaxf(Km, __shfl_xor(Km, s));
    float wj = (l < 32) ? al * exp2f(KA - Km) : 0.f;
    float t1 = 0.f;
    for (int j = 0; j < 32; ++j) t1 += P[OF_MC + 33 * j + (l & 31)] * __shfl(wj, j);
    Kacc += Km;

    float vv = (l < 32) ? P[OF_BWD + l] : 0.f;
    float s = vv * t1;
    #pragma unroll
    for (int mm = 1; mm < 64; mm <<= 1) s += __shfl_xor(s, mm);
    float fcc = __logf(s) + Kacc * LN2F;

    // ---- FAC: score = sum_s alpha[s] * beta[s] ----
    float pa = P[OF_FACF + 4 * l + 0] * P[OF_FACB + 4 * l + 0]
             + P[OF_FACF + 4 * l + 1] * P[OF_FACB + 4 * l + 1]
             + P[OF_FACF + 4 * l + 2] * P[OF_FACB + 4 * l + 2]
             + P[OF_FACF + 4 * l + 3] * P[OF_FACB + 4 * l + 3];
    float sc = P[OF_FACF + 256 + l] + P[OF_FACB + 256 + l];
    float Ms = sc;
    #pragma unroll
    for (int mm = 1; mm < 64; mm <<= 1) Ms = fmaxf(Ms, __shfl_xor(Ms, mm));
    float pp = pa * exp2f(sc - Ms);
    #pragma unroll
    for (int mm = 1; mm < 64; mm <<= 1) pp += __shfl_xor(pp, mm);
    float fac = __logf(pp) + Ms * LN2F;

    if (l == 0) sd[b] = fcc - fac;
  }
  __syncthreads();
  if (tid < TB) {
    float d = sd[tid];
    #pragma unroll
    for (int mm = 1; mm < 64; mm <<= 1) d += __shfl_xor(d, mm);
    if (tid == 0) out[0] = d * (1.0f / TB);
  }
}

// ======================= launcher =======================================

extern "C" void kernel_launch(void* const* d_in, const int* in_sizes, int n_in,
                              void* d_out, int out_size, void* d_ws, size_t ws_size,
                              hipStream_t stream) {
  const float* trans   = (const float*)d_in[0];
  const float* inputs  = (const float*)d_in[1];
  const int*   targets = (const int*)d_in[2];
  const int*   ilen    = (const int*)d_in[3];
  const int*   tlen    = (const int*)d_in[4];
  float* out = (float*)d_out;
  float* ws  = (float*)d_ws;

  // 256 basis blocks (8 column-waves) + 256 role blocks (chain+helpers)
  asg_main<<<dim3(8 * TB), dim3(512), 0, stream>>>(trans, inputs, targets, ilen, tlen, ws);
  asg_combine<<<dim3(1), dim3(1024), 0, stream>>>(ws, out);
}

// Round 5
// 97.630 us; speedup vs baseline: 1.4965x; 1.4965x over previous
//
#include <hip/hip_runtime.h>
#include <math.h>

static constexpr int TB = 64;   // batch
static constexpr int LL = 32;   // labels
static constexpr int SS = 256;  // max target length
static constexpr int STRIDE_T = TB * LL;  // floats per time step (2048)

// FCC chunking: 8 chunks -> chunk0 (fwd, init), 6 interior (fwd+bwd), last (bwd)
static constexpr int NCH = 8;
static constexpr int NI  = NCH - 2;             // 6 interior
static constexpr int NSCAN = 2 + 2 * NI;        // 14 scans per batch

// ---- workspace layout (floats per batch) --------------------------------
// FCC slots (33 floats each: 32 vec + K): 0=a, 1=c, 2j=p_j, 2j+1=q_j (j=1..6)
static constexpr int OF_FCC  = 0;               // 14*33 = 462
static constexpr int OF_FACF = 512;             // 256 vals + 64 scales
static constexpr int OF_FACB = 832;             // 256 vals + 64 scales
static constexpr int WSB     = 1152;            // per-batch stride

#define LN2F 0.69314718055994530942f
#define NEGF (-1e30f)

// raw barrier: waits LDS only (keeps global-load prefetch in flight)
#define BARX() { asm volatile("s_waitcnt lgkmcnt(0)" ::: "memory"); \
                 __builtin_amdgcn_s_barrier(); \
                 asm volatile("" ::: "memory"); }

// ---- DPP / cross-lane helpers ------------------------------------------
template<int CTL>
__device__ __forceinline__ float dpp_f(float x, float oldv) {
  return __int_as_float(__builtin_amdgcn_update_dpp(
      __float_as_int(oldv), __float_as_int(x), CTL, 0xF, 0xF, false));
}
template<int M>
__device__ __forceinline__ int rot_i(int x) {
  return __builtin_amdgcn_update_dpp(0, x, 0x120 + M, 0xF, 0xF, false); // row_ror:M
}

typedef unsigned uint2v __attribute__((ext_vector_type(2)));
__device__ __forceinline__ float xsum16(float x) {  // x[l] + x[l^16]
  uint2v r = __builtin_amdgcn_permlane16_swap(__float_as_uint(x), __float_as_uint(x), false, false);
  return __uint_as_float(r.x) + __uint_as_float(r.y);
}
__device__ __forceinline__ float xsum32(float x) {  // x[l] + x[l^32]
  uint2v r = __builtin_amdgcn_permlane32_swap(__float_as_uint(x), __float_as_uint(x), false, false);
  return __uint_as_float(r.x) + __uint_as_float(r.y);
}
__device__ __forceinline__ float bperm(int addr, float src) {  // pull lane addr>>2
  return __int_as_float(__builtin_amdgcn_ds_bpermute(addr, __float_as_int(src)));
}

// Self-calibrating coefficient load (rot_i matches row_ror:M exactly)
template<int M>
struct Calib {
  __device__ static __forceinline__ void run(const float* trans, int lam, int i, float* Ec) {
    Ec[M] = __expf(trans[i * LL + rot_i<M>(lam)]);
    Calib<M + 1>::run(trans, lam, i, Ec);
  }
};
template<> struct Calib<16> {
  __device__ static __forceinline__ void run(const float*, int, int, float*) {}
};
// Transposed variant: coefficient trans[rot(lam)][i]  (M^T matvec)
template<int M>
struct CalibT {
  __device__ static __forceinline__ void run(const float* trans, int lam, int i, float* Ec) {
    Ec[M] = __expf(trans[rot_i<M>(lam) * LL + i]);
    CalibT<M + 1>::run(trans, lam, i, Ec);
  }
};
template<> struct CalibT<16> {
  __device__ static __forceinline__ void run(const float*, int, int, float*) {}
};

// ---- fused rotate-multiply asm (1 instr per term) -----------------------
#define ROT_MUL(DST, SRC, COEF, ROT) \
  asm("v_mul_f32_dpp %0, %1, %2 row_ror:" #ROT " row_mask:0xf bank_mask:0xf" \
      : "=v"(DST) : "v"(SRC), "v"(COEF))
#define ROT_FMAC(ACC, SRC, COEF, ROT) \
  asm("v_fmac_f32_dpp %0, %1, %2 row_ror:" #ROT " row_mask:0xf bank_mask:0xf" \
      : "+v"(ACC) : "v"(SRC), "v"(COEF))

// matvec over 16-lane rows: 8 indep chains of depth 2, then 3-level tree
#define STEP16(EC) { \
  float a0 = EC[0] * A, a1, a2, a3, a4, a5, a6, a7; \
  ROT_MUL(a1, A, EC[1], 1); ROT_MUL(a2, A, EC[2], 2); ROT_MUL(a3, A, EC[3], 3); \
  ROT_MUL(a4, A, EC[4], 4); ROT_MUL(a5, A, EC[5], 5); ROT_MUL(a6, A, EC[6], 6); \
  ROT_MUL(a7, A, EC[7], 7); \
  ROT_FMAC(a0, A, EC[8], 8);   ROT_FMAC(a1, A, EC[9], 9); \
  ROT_FMAC(a2, A, EC[10], 10); ROT_FMAC(a3, A, EC[11], 11); \
  ROT_FMAC(a4, A, EC[12], 12); ROT_FMAC(a5, A, EC[13], 13); \
  ROT_FMAC(a6, A, EC[14], 14); ROT_FMAC(a7, A, EC[15], 15); \
  part = ((a0 + a1) + (a2 + a3)) + ((a4 + a5) + (a6 + a7)); }

// ======================= FCC chain ======================================

#define FCC_RENORM() { \
  unsigned uu = (unsigned)__builtin_amdgcn_readfirstlane((int)__float_as_uint(A)); \
  int ex = (int)((uu >> 23) & 255) - 127; \
  A = ldexpf(A, -ex); Kt += ex; }

#define FCC_CONSUME8(PB) { \
  float eb[8]; \
  _Pragma("unroll") for (int q = 0; q < 8; ++q) eb[q] = sE[PB][q][(q & 1) ? lam1 : lam2]; \
  { float part; STEP16(Ec1); A = eb[0] * xsum16(part); } \
  { float part; STEP16(Ec2); A = eb[1] * xsum32(part); } \
  { float part; STEP16(Ec1); A = eb[2] * xsum16(part); } \
  { float part; STEP16(Ec2); A = eb[3] * xsum32(part); } \
  { float part; STEP16(Ec1); A = eb[4] * xsum16(part); } \
  { float part; STEP16(Ec2); A = eb[5] * xsum32(part); } \
  { float part; STEP16(Ec1); A = eb[6] * xsum16(part); } \
  { float part; STEP16(Ec2); A = eb[7] * xsum32(part); } \
  FCC_RENORM(); }

#define FCC_TAIL8(PB, CNT) { \
  float eb[8]; \
  _Pragma("unroll") for (int q = 0; q < 8; ++q) eb[q] = sE[PB][q][(q & 1) ? lam1 : lam2]; \
  _Pragma("unroll") for (int q = 0; q < 8; ++q) { \
    if (q >= (CNT)) break; \
    if ((q & 1) == 0) { float part; STEP16(Ec1); A = eb[q] * xsum16(part); } \
    else              { float part; STEP16(Ec2); A = eb[q] * xsum32(part); } } }

// backward (transpose): consumes rows 7..0; emission multiplies BEFORE matvec
#define FCC_BWDCON8(PB) { \
  float eb[8]; \
  _Pragma("unroll") for (int q = 0; q < 8; ++q) eb[q] = sE[PB][q][(q & 1) ? lam1 : lam2]; \
  { A *= eb[7]; float part; STEP16(E1T); A = xsum16(part); } \
  { A *= eb[6]; float part; STEP16(E2T); A = xsum32(part); } \
  { A *= eb[5]; float part; STEP16(E1T); A = xsum16(part); } \
  { A *= eb[4]; float part; STEP16(E2T); A = xsum32(part); } \
  { A *= eb[3]; float part; STEP16(E1T); A = xsum16(part); } \
  { A *= eb[2]; float part; STEP16(E2T); A = xsum32(part); } \
  { A *= eb[1]; float part; STEP16(E1T); A = xsum16(part); } \
  { A *= eb[0]; float part; STEP16(E2T); A = xsum32(part); } \
  FCC_RENORM(); }

// ======================= FAC chain (premultiplied coefficients) =========
// sFa[.][r][l] = {E0*ST0, E1*ST1, E2*ST2, E3*ST3}
// fwd: sFb = {E0*MV0, E1*MV1, E2*MV2, E3*MV3}   (MV0 = move into 4l from 4l-1)
// bwd: sFb = {E1*MVn0, E2*MVn1, E3*MVn2, Enext*MVn3}

#define FAC_BOUNDARY_S() { \
  float maxA = fmaxf(fmaxf(A0, A1), fmaxf(A2, A3)); \
  if (maxA > 0.f) { \
    int ex = (int)((__float_as_uint(maxA) >> 23) & 255) - 127; \
    A0 = ldexpf(A0, -ex); A1 = ldexpf(A1, -ex); \
    A2 = ldexpf(A2, -ex); A3 = ldexpf(A3, -ex); \
    m += (float)ex; \
  } \
  float mp = dpp_f<0x138>(m, NEGF); m = (m == NEGF) ? mp : m; \
  mp = dpp_f<0x138>(m, NEGF);       m = (m == NEGF) ? mp : m; \
  mp = dpp_f<0x138>(m, NEGF); \
  float dlt = fminf(mp - m, 50.0f); \
  Sin = exp2f(dlt); }

#define FACF_CON8(PB) { \
  float4 Sr[8], Mr[8]; \
  _Pragma("unroll") for (int r = 0; r < 8; ++r) { Sr[r] = sFa[PB][r][l]; Mr[r] = sFb[PB][r][l]; } \
  _Pragma("unroll") for (int r = 0; r < 8; ++r) { \
    float t0 = Mr[r].x * Sin; \
    float ap = dpp_f<0x138>(A3, 0.f); /* wave_shr:1 */ \
    float n0 = fmaf(t0,      ap, Sr[r].x * A0); \
    float n1 = fmaf(Mr[r].y, A0, Sr[r].y * A1); \
    float n2 = fmaf(Mr[r].z, A1, Sr[r].z * A2); \
    float n3 = fmaf(Mr[r].w, A2, Sr[r].w * A3); \
    A0 = n0; A1 = n1; A2 = n2; A3 = n3; } \
  FAC_BOUNDARY_S(); }

#define FACF_TAIL8(PB, CNT) { \
  float4 Sr[8], Mr[8]; \
  _Pragma("unroll") for (int r = 0; r < 8; ++r) { Sr[r] = sFa[PB][r][l]; Mr[r] = sFb[PB][r][l]; } \
  _Pragma("unroll") for (int r = 0; r < 8; ++r) { \
    if (r >= (CNT)) break; \
    float t0 = Mr[r].x * Sin; \
    float ap = dpp_f<0x138>(A3, 0.f); \
    float n0 = fmaf(t0,      ap, Sr[r].x * A0); \
    float n1 = fmaf(Mr[r].y, A0, Sr[r].y * A1); \
    float n2 = fmaf(Mr[r].z, A1, Sr[r].z * A2); \
    float n3 = fmaf(Mr[r].w, A2, Sr[r].w * A3); \
    A0 = n0; A1 = n1; A2 = n2; A3 = n3; } }

#define FACB_BOUNDARY_S() { \
  float maxA = fmaxf(fmaxf(A0, A1), fmaxf(A2, A3)); \
  if (maxA > 0.f) { \
    int ex = (int)((__float_as_uint(maxA) >> 23) & 255) - 127; \
    A0 = ldexpf(A0, -ex); A1 = ldexpf(A1, -ex); \
    A2 = ldexpf(A2, -ex); A3 = ldexpf(A3, -ex); \
    m += (float)ex; \
  } \
  float mp = dpp_f<0x130>(m, NEGF); m = (m == NEGF) ? mp : m; \
  mp = dpp_f<0x130>(m, NEGF);       m = (m == NEGF) ? mp : m; \
  mp = dpp_f<0x130>(m, NEGF); \
  float dlt = fminf(mp - m, 50.0f); \
  Sb = exp2f(dlt); }

#define FACB_CON8(PB) { \
  float4 Sr[8], Mr[8]; \
  _Pragma("unroll") for (int r = 0; r < 8; ++r) { Sr[r] = sFa[PB][r][l]; Mr[r] = sFb[PB][r][l]; } \
  _Pragma("unroll") for (int i = 0; i < 8; ++i) { \
    const int q = 7 - i; \
    float t3 = Mr[q].w * Sb; \
    float an = dpp_f<0x130>(A0, 0.f); /* wave_shl:1 */ \
    float n0 = fmaf(Mr[q].x, A1, Sr[q].x * A0); \
    float n1 = fmaf(Mr[q].y, A2, Sr[q].y * A1); \
    float n2 = fmaf(Mr[q].z, A3, Sr[q].z * A2); \
    float n3 = fmaf(t3,      an, Sr[q].w * A3); \
    A0 = n0; A1 = n1; A2 = n2; A3 = n3; } \
  FACB_BOUNDARY_S(); }

// ======================= staging loads ==================================

// fwd: phase Q rows start at t0 + 8Q; pair K = rows 2K,2K+1 (via rowoff)
#define HLDF(Q, K) ({ \
  int tt_ = t0 + 8 * (Q) + 2 * (K) + rowoff; \
  tt_ = tt_ > lenm1 ? lenm1 : tt_; \
  gpl[(size_t)tt_ * STRIDE_T]; })
// bwd: phase Q rows are [thi-8Q-7, thi-8Q]
#define HLDB(Q, K) ({ \
  int tt_ = thi - 8 * (Q) - 7 + 2 * (K) + rowoff; \
  tt_ = tt_ < 0 ? 0 : (tt_ > lenm1 ? lenm1 : tt_); \
  gpl[(size_t)tt_ * STRIDE_T]; })
#define HLD2(Q, K) ( isfwd ? HLDF(Q, K) : HLDB(Q, K) )

#define PROD_FCC(PB, KK, RV) { sE[PB][2 * (KK) + rowoff][lam1] = __expf(RV); }

// FAC helper produce: one loaded value covers 2 rows (lane halves)
#define PRODF_FWD(PB, KK, RV) { \
  float e_ = __expf(RV); \
  float c0 = bperm(adA[0], e_), c1 = bperm(adA[1], e_); \
  float c2 = bperm(adA[2], e_), c3 = bperm(adA[3], e_); \
  float4 sa, sb; \
  sa.x = c0 * ST[0]; sa.y = c1 * ST[1]; sa.z = c2 * ST[2]; sa.w = c3 * ST[3]; \
  sb.x = c0 * CM[0]; sb.y = c1 * CM[1]; sb.z = c2 * CM[2]; sb.w = c3 * CM[3]; \
  sFa[PB][2 * (KK)][l] = sa; sFb[PB][2 * (KK)][l] = sb; \
  float d0 = bperm(adB[0], e_), d1 = bperm(adB[1], e_); \
  float d2 = bperm(adB[2], e_), d3 = bperm(adB[3], e_); \
  sa.x = d0 * ST[0]; sa.y = d1 * ST[1]; sa.z = d2 * ST[2]; sa.w = d3 * ST[3]; \
  sb.x = d0 * CM[0]; sb.y = d1 * CM[1]; sb.z = d2 * CM[2]; sb.w = d3 * CM[3]; \
  sFa[PB][2 * (KK) + 1][l] = sa; sFb[PB][2 * (KK) + 1][l] = sb; }

#define PRODF_BWD(PB, KK, RV) { \
  float e_ = __expf(RV); \
  float c0 = bperm(adA[0], e_), c1 = bperm(adA[1], e_); \
  float c2 = bperm(adA[2], e_), c3 = bperm(adA[3], e_); \
  float cn = bperm(adN, e_); \
  float4 sa, sb; \
  sa.x = c0 * ST[0]; sa.y = c1 * ST[1]; sa.z = c2 * ST[2]; sa.w = c3 * ST[3]; \
  sb.x = c1 * CM[0]; sb.y = c2 * CM[1]; sb.z = c3 * CM[2]; sb.w = cn * CM[3]; \
  sFa[PB][2 * (KK)][l] = sa; sFb[PB][2 * (KK)][l] = sb; \
  float d0 = bperm(adB[0], e_), d1 = bperm(adB[1], e_); \
  float d2 = bperm(adB[2], e_), d3 = bperm(adB[3], e_); \
  float dn = bperm(adNB, e_); \
  sa.x = d0 * ST[0]; sa.y = d1 * ST[1]; sa.z = d2 * ST[2]; sa.w = d3 * ST[3]; \
  sb.x = d1 * CM[0]; sb.y = d2 * CM[1]; sb.z = d3 * CM[2]; sb.w = dn * CM[3]; \
  sFa[PB][2 * (KK) + 1][l] = sa; sFb[PB][2 * (KK) + 1][l] = sb; }

// ======================= main kernel ====================================
// grid: [0, 14*64)      = FCC chunk scans (chain + 1 helper + 1 dummy)
//       [14*64, 16*64)  = FAC halves     (chain + 2 helpers)

extern "C" __global__ __launch_bounds__(192, 1)
void asg_main(const float* __restrict__ trans, const float* __restrict__ inputs,
              const int* __restrict__ targets, const int* __restrict__ ilen,
              const int* __restrict__ tlen, float* __restrict__ ws) {
  const int tid = (int)threadIdx.x;
  const int w = tid >> 6;
  const int l = tid & 63;
  const int lam1 = l & 31;
  const int lam2 = (l & 15) | ((l >> 5) << 4);
  const int rowoff = l >> 5;
  const int bid = (int)blockIdx.x;

  __shared__ float  sE[2][8][32];    // FCC emission staging (2 KB)
  __shared__ float4 sFa[2][8][64];   // FAC E*stay (16 KB)
  __shared__ float4 sFb[2][8][64];   // FAC E*move (16 KB)

  if (bid < NSCAN * TB) {
    // ================= FCC chunk scans ================================
    const int s = bid >> 6;          // scan id 0..13
    const int b = bid & 63;
    const int len = ilen[b];
    const int lenm1 = len - 1;
    const int Lsteps = lenm1;
    const int L  = (Lsteps / NCH) & ~7;          // interior/last chunk length
    const int n0 = Lsteps - (NCH - 1) * L;       // chunk0 length (has tail)

    bool isfwd; int t0 = 1, thi = lenm1, nsteps, outslot;
    if (s == 0)      { isfwd = true;  t0 = 1; nsteps = n0; outslot = 0; }
    else if (s == 1) { isfwd = false; thi = lenm1; nsteps = L; outslot = 1; }
    else {
      const int j = s >> 1;                      // 1..6
      if ((s & 1) == 0) { isfwd = true;  t0 = n0 + (j - 1) * L + 1; nsteps = L; outslot = 2 * j; }
      else              { isfwd = false; thi = n0 + j * L;          nsteps = L; outslot = 2 * j + 1; }
    }
    const int nph = (nsteps + 7) >> 3;
    const float* gpl = inputs + (size_t)b * LL + lam1;
    float* P = ws + (size_t)b * WSB + OF_FCC + outslot * 33;

    if (w == 0) {
      __builtin_amdgcn_s_setprio(1);
      if (isfwd) {
        float Ec1[16], Ec2[16];
        Ec1[0] = __expf(trans[lam2 * LL + lam1]);
        Ec2[0] = __expf(trans[lam1 * LL + lam2]);
        Calib<1>::run(trans, lam1, lam2, Ec1);
        Calib<1>::run(trans, lam2, lam1, Ec2);
        float A = (s == 0) ? __expf(inputs[(size_t)b * LL + lam1]) : 1.f;
        int Kt = 0;
        for (int p = 0; p < nph; p += 2) {
          BARX();
          { const int rem = nsteps - 8 * p;
            if (rem >= 8) { FCC_CONSUME8(0); } else { FCC_TAIL8(0, rem); } }
          BARX();
          if (p + 1 < nph) {
            const int rem = nsteps - 8 * (p + 1);
            if (rem >= 8) { FCC_CONSUME8(1); } else { FCC_TAIL8(1, rem); }
          }
        }
        const int par = nsteps & 1;
        const int idx = par ? lam2 : lam1;
        const bool wr = par ? ((l & 16) == 0) : (l < 32);
        if (wr) P[idx] = A;
        if (l == 0) P[32] = (float)Kt;
      } else {
        float E1T[16], E2T[16];
        E1T[0] = __expf(trans[lam1 * LL + lam2]);
        E2T[0] = __expf(trans[lam2 * LL + lam1]);
        CalibT<1>::run(trans, lam1, lam2, E1T);
        CalibT<1>::run(trans, lam2, lam1, E2T);
        float A = 1.f;
        int Kt = 0;
        for (int p = 0; p < nph; p += 2) {
          BARX();
          FCC_BWDCON8(0);
          BARX();
          if (p + 1 < nph) { FCC_BWDCON8(1); }
        }
        if (l < 32) P[lam1] = A;      // L mult of 8 -> lam1 layout
        if (l == 0) P[32] = (float)Kt;
      }
    } else if (w == 1) {
      // single helper stages all 4 pairs, 3-deep prefetch
      float R1[4], R2[4], R3[4];
      #pragma unroll
      for (int k = 0; k < 4; ++k) R1[k] = HLD2(0, k);
      #pragma unroll
      for (int k = 0; k < 4; ++k) R2[k] = HLD2(1, k);
      #pragma unroll
      for (int k = 0; k < 4; ++k) R3[k] = HLD2(2, k);
      #pragma unroll
      for (int k = 0; k < 4; ++k) PROD_FCC(0, k, R1[k]);
      #pragma unroll
      for (int k = 0; k < 4; ++k) { R1[k] = R2[k]; R2[k] = R3[k]; R3[k] = HLD2(3, k); }
      for (int p = 0; p < nph; p += 2) {
        BARX();
        if (p + 1 < nph) {
          float N[4];
          #pragma unroll
          for (int k = 0; k < 4; ++k) N[k] = HLD2(p + 4, k);
          #pragma unroll
          for (int k = 0; k < 4; ++k) PROD_FCC(1, k, R1[k]);
          #pragma unroll
          for (int k = 0; k < 4; ++k) { R1[k] = R2[k]; R2[k] = R3[k]; R3[k] = N[k]; }
        }
        BARX();
        if (p + 2 < nph) {
          float N[4];
          #pragma unroll
          for (int k = 0; k < 4; ++k) N[k] = HLD2(p + 5, k);
          #pragma unroll
          for (int k = 0; k < 4; ++k) PROD_FCC(0, k, R1[k]);
          #pragma unroll
          for (int k = 0; k < 4; ++k) { R1[k] = R2[k]; R2[k] = R3[k]; R3[k] = N[k]; }
        }
      }
    } else {
      // dummy: barrier participation only
      const int I = (nph + 1) >> 1;
      for (int i = 0; i < I; ++i) { BARX(); BARX(); }
    }
    return;
  }

  // ================= FAC halves =======================================
  const int rid  = bid - NSCAN * TB;
  const int role = rid >> 6;   // 0 fwd, 1 bwd
  const int b    = rid & 63;

  const int len = ilen[b];
  const int lenm1 = len - 1;
  const int Lsteps = lenm1;
  const int nbf = (Lsteps / 2) & ~7;
  const int nff = Lsteps - nbf;
  const bool isfwd = (role == 0);
  const int t0 = 1, thi = lenm1;
  const int nsteps = isfwd ? nff : nbf;
  const int nph = (nsteps + 7) >> 3;

  const float* gpl = inputs + (size_t)b * LL + lam1;
  float* P = ws + (size_t)b * WSB;

  if (w == 0) {
    __builtin_amdgcn_s_setprio(1);
    if (isfwd) {
      const int tg0 = targets[b * SS + 4 * l];
      float A0 = (l == 0) ? __expf(inputs[(size_t)b * LL + tg0]) : 0.f;
      float A1 = 0.f, A2 = 0.f, A3 = 0.f;
      float m  = (l == 0) ? 0.f : NEGF;
      float Sin;
      FAC_BOUNDARY_S();
      for (int p = 0; p < nph; p += 2) {
        BARX();
        { const int rem = nsteps - 8 * p;
          if (rem >= 8) { FACF_CON8(0); } else { FACF_TAIL8(0, rem); } }
        BARX();
        if (p + 1 < nph) {
          const int rem = nsteps - 8 * (p + 1);
          if (rem >= 8) { FACF_CON8(1); } else { FACF_TAIL8(1, rem); }
        }
      }
      P[OF_FACF + 4 * l + 0] = A0;
      P[OF_FACF + 4 * l + 1] = A1;
      P[OF_FACF + 4 * l + 2] = A2;
      P[OF_FACF + 4 * l + 3] = A3;
      P[OF_FACF + 256 + l]   = m;
    } else {
      const int tl = tlen[b];
      const int fs = tl - 1;
      float A0 = (4 * l + 0 == fs) ? 1.f : 0.f;
      float A1 = (4 * l + 1 == fs) ? 1.f : 0.f;
      float A2 = (4 * l + 2 == fs) ? 1.f : 0.f;
      float A3 = (4 * l + 3 == fs) ? 1.f : 0.f;
      float m  = (l == (fs >> 2)) ? 0.f : NEGF;
      float Sb;
      FACB_BOUNDARY_S();
      for (int p = 0; p < nph; p += 2) {
        BARX();
        FACB_CON8(0);
        BARX();
        if (p + 1 < nph) { FACB_CON8(1); }
      }
      P[OF_FACB + 4 * l + 0] = A0;
      P[OF_FACB + 4 * l + 1] = A1;
      P[OF_FACB + 4 * l + 2] = A2;
      P[OF_FACB + 4 * l + 3] = A3;
      P[OF_FACB + 256 + l]   = m;
    }
  } else {
    // 2 helper waves, 2 row-pairs each, premultiplied coefficients
    const int kh = 2 * (w - 1);
    int tg[4];
    #pragma unroll
    for (int q = 0; q < 4; ++q) tg[q] = targets[b * SS + 4 * l + q];
    float ST[4], CM[4];
    #pragma unroll
    for (int q = 0; q < 4; ++q) ST[q] = __expf(trans[tg[q] * LL + tg[q]]);
    int adA[4], adB[4], adN = 0, adNB = 0;
    #pragma unroll
    for (int j = 0; j < 4; ++j) { adA[j] = tg[j] * 4; adB[j] = adA[j] + 128; }
    if (isfwd) {
      CM[0] = (l == 0) ? 0.f : __expf(trans[tg[0] * LL + targets[b * SS + 4 * l - 1]]);
      #pragma unroll
      for (int q = 1; q < 4; ++q) CM[q] = __expf(trans[tg[q] * LL + tg[q - 1]]);
    } else {
      CM[0] = __expf(trans[tg[1] * LL + tg[0]]);
      CM[1] = __expf(trans[tg[2] * LL + tg[1]]);
      CM[2] = __expf(trans[tg[3] * LL + tg[2]]);
      int tgn3 = (l < 63) ? targets[b * SS + 4 * l + 4] : 0;
      CM[3] = (l < 63) ? __expf(trans[tgn3 * LL + tg[3]]) : 0.f;
      adN = tgn3 * 4; adNB = adN + 128;
    }

    float R1a = HLD2(0, kh), R1b = HLD2(0, kh + 1);
    float R2a = HLD2(1, kh), R2b = HLD2(1, kh + 1);
    float R3a = HLD2(2, kh), R3b = HLD2(2, kh + 1);
    if (isfwd) { PRODF_FWD(0, kh, R1a); PRODF_FWD(0, kh + 1, R1b); }
    else       { PRODF_BWD(0, kh, R1a); PRODF_BWD(0, kh + 1, R1b); }
    R1a = R2a; R1b = R2b; R2a = R3a; R2b = R3b;
    R3a = HLD2(3, kh); R3b = HLD2(3, kh + 1);

    for (int p = 0; p < nph; p += 2) {
      BARX();
      if (p + 1 < nph) {
        float Na = HLD2(p + 4, kh), Nb = HLD2(p + 4, kh + 1);
        if (isfwd) { PRODF_FWD(1, kh, R1a); PRODF_FWD(1, kh + 1, R1b); }
        else       { PRODF_BWD(1, kh, R1a); PRODF_BWD(1, kh + 1, R1b); }
        R1a = R2a; R1b = R2b; R2a = R3a; R2b = R3b; R3a = Na; R3b = Nb;
      }
      BARX();
      if (p + 2 < nph) {
        float Na = HLD2(p + 5, kh), Nb = HLD2(p + 5, kh + 1);
        if (isfwd) { PRODF_FWD(0, kh, R1a); PRODF_FWD(0, kh + 1, R1b); }
        else       { PRODF_BWD(0, kh, R1a); PRODF_BWD(0, kh + 1, R1b); }
        R1a = R2a; R1b = R2b; R2a = R3a; R2b = R3b; R3a = Na; R3b = Nb;
      }
    }
  }
}

// ======================= combine ========================================

extern "C" __global__ __launch_bounds__(1024)
void asg_combine(const float* __restrict__ ws, float* __restrict__ out) {
  __shared__ float sd[TB];
  const int tid = (int)threadIdx.x;
  const int w = tid >> 6, l = tid & 63;

  for (int k = 0; k < 4; ++k) {
    const int b = w * 4 + k;
    const float* P = ws + (size_t)b * WSB;

    // ---- FCC: telescoped rank-1 chunk products ----
    // fcc = log(q1.a) + sum_j log(q_{j+1}.p_j) + log(c.p_NI)
    //       - sum_j log(sum(p_j)) + LN2*(Ka + Kc + sum Kq_j)
    float acc = 0.f;
    float Ksum = P[OF_FCC + 0 * 33 + 32];           // Ka
    #pragma unroll
    for (int j = 0; j <= NI; ++j) {
      const int qs = (j == NI) ? 1 : (2 * j + 3);   // q_{j+1}, last = c
      const int ps = (j == 0) ? 0 : (2 * j);        // p_j, first = a
      float qv = (l < 32) ? P[OF_FCC + qs * 33 + l] : 0.f;
      float pv = (l < 32) ? P[OF_FCC + ps * 33 + l] : 0.f;
      float d = qv * pv;
      #pragma unroll
      for (int mm = 1; mm < 64; mm <<= 1) d += __shfl_xor(d, mm);
      acc += __logf(d);
      Ksum += P[OF_FCC + qs * 33 + 32];             // Kq (or Kc)
    }
    #pragma unroll
    for (int j = 1; j <= NI; ++j) {
      float pv = (l < 32) ? P[OF_FCC + 2 * j * 33 + l] : 0.f;
      #pragma unroll
      for (int mm = 1; mm < 64; mm <<= 1) pv += __shfl_xor(pv, mm);
      acc -= __logf(pv);
    }
    float fcc = acc + Ksum * LN2F;

    // ---- FAC: score = sum_s alpha[s] * beta[s] ----
    float pa = P[OF_FACF + 4 * l + 0] * P[OF_FACB + 4 * l + 0]
             + P[OF_FACF + 4 * l + 1] * P[OF_FACB + 4 * l + 1]
             + P[OF_FACF + 4 * l + 2] * P[OF_FACB + 4 * l + 2]
             + P[OF_FACF + 4 * l + 3] * P[OF_FACB + 4 * l + 3];
    float sc = P[OF_FACF + 256 + l] + P[OF_FACB + 256 + l];
    float Ms = sc;
    #pragma unroll
    for (int mm = 1; mm < 64; mm <<= 1) Ms = fmaxf(Ms, __shfl_xor(Ms, mm));
    float pp = pa * exp2f(sc - Ms);
    #pragma unroll
    for (int mm = 1; mm < 64; mm <<= 1) pp += __shfl_xor(pp, mm);
    float fac = __logf(pp) + Ms * LN2F;

    if (l == 0) sd[b] = fcc - fac;
  }
  __syncthreads();
  if (tid < TB) {
    float d = sd[tid];
    #pragma unroll
    for (int mm = 1; mm < 64; mm <<= 1) d += __shfl_xor(d, mm);
    if (tid == 0) out[0] = d * (1.0f / TB);
  }
}

// ======================= launcher =======================================

extern "C" void kernel_launch(void* const* d_in, const int* in_sizes, int n_in,
                              void* d_out, int out_size, void* d_ws, size_t ws_size,
                              hipStream_t stream) {
  const float* trans   = (const float*)d_in[0];
  const float* inputs  = (const float*)d_in[1];
  const int*   targets = (const int*)d_in[2];
  const int*   ilen    = (const int*)d_in[3];
  const int*   tlen    = (const int*)d_in[4];
  float* out = (float*)d_out;
  float* ws  = (float*)d_ws;

  // 14*64 FCC chunk scans + 2*64 FAC halves, 3 waves per block
  asg_main<<<dim3((NSCAN + 2) * TB), dim3(192), 0, stream>>>(
      trans, inputs, targets, ilen, tlen, ws);
  asg_combine<<<dim3(1), dim3(1024), 0, stream>>>(ws, out);
}

// Round 6
// 92.847 us; speedup vs baseline: 1.5736x; 1.0515x over previous
//
#include <hip/hip_runtime.h>
#include <math.h>

static constexpr int TB = 64;   // batch
static constexpr int LL = 32;   // labels
static constexpr int SS = 256;  // max target length
static constexpr int STRIDE_T = TB * LL;  // floats per time step (2048)

// FCC chunking: 8 chunks -> chunk0 (fwd, init), 6 interior (fwd+bwd), last (bwd)
static constexpr int NCH = 8;
static constexpr int NI  = NCH - 2;             // 6 interior
static constexpr int NSCAN = 2 + 2 * NI;        // 14 scans per batch

// ---- workspace layout (floats per batch) --------------------------------
// FCC slots (33 floats each: 32 vec + K): 0=a, 1=c, 2j=p_j, 2j+1=q_j (j=1..6)
static constexpr int OF_FCC  = 0;               // 14*33 = 462
static constexpr int OF_FACF = 512;             // 256 vals + 64 scales
static constexpr int OF_FACB = 832;             // 256 vals + 64 scales
static constexpr int WSB     = 1152;            // per-batch stride

#define LN2F 0.69314718055994530942f
#define NEGF (-1e30f)

// raw barrier: waits LDS only (keeps global-load prefetch in flight)
#define BARX() { asm volatile("s_waitcnt lgkmcnt(0)" ::: "memory"); \
                 __builtin_amdgcn_s_barrier(); \
                 asm volatile("" ::: "memory"); }

// ---- DPP / cross-lane helpers ------------------------------------------
template<int CTL>
__device__ __forceinline__ float dpp_f(float x, float oldv) {
  return __int_as_float(__builtin_amdgcn_update_dpp(
      __float_as_int(oldv), __float_as_int(x), CTL, 0xF, 0xF, false));
}
template<int M>
__device__ __forceinline__ int rot_i(int x) {
  return __builtin_amdgcn_update_dpp(0, x, 0x120 + M, 0xF, 0xF, false); // row_ror:M
}

typedef unsigned uint2v __attribute__((ext_vector_type(2)));
__device__ __forceinline__ float xsum16(float x) {  // x[l] + x[l^16]
  uint2v r = __builtin_amdgcn_permlane16_swap(__float_as_uint(x), __float_as_uint(x), false, false);
  return __uint_as_float(r.x) + __uint_as_float(r.y);
}
__device__ __forceinline__ float xsum32(float x) {  // x[l] + x[l^32]
  uint2v r = __builtin_amdgcn_permlane32_swap(__float_as_uint(x), __float_as_uint(x), false, false);
  return __uint_as_float(r.x) + __uint_as_float(r.y);
}
__device__ __forceinline__ float bperm(int addr, float src) {  // pull lane addr>>2
  return __int_as_float(__builtin_amdgcn_ds_bpermute(addr, __float_as_int(src)));
}

// Self-calibrating coefficient load (rot_i matches row_ror:M exactly)
template<int M>
struct Calib {
  __device__ static __forceinline__ void run(const float* trans, int lam, int i, float* Ec) {
    Ec[M] = __expf(trans[i * LL + rot_i<M>(lam)]);
    Calib<M + 1>::run(trans, lam, i, Ec);
  }
};
template<> struct Calib<16> {
  __device__ static __forceinline__ void run(const float*, int, int, float*) {}
};
// Transposed variant: coefficient trans[rot(lam)][i]  (M^T matvec)
template<int M>
struct CalibT {
  __device__ static __forceinline__ void run(const float* trans, int lam, int i, float* Ec) {
    Ec[M] = __expf(trans[rot_i<M>(lam) * LL + i]);
    CalibT<M + 1>::run(trans, lam, i, Ec);
  }
};
template<> struct CalibT<16> {
  __device__ static __forceinline__ void run(const float*, int, int, float*) {}
};

// ---- fused rotate-multiply asm (1 instr per term) -----------------------
#define ROT_MUL(DST, SRC, COEF, ROT) \
  asm("v_mul_f32_dpp %0, %1, %2 row_ror:" #ROT " row_mask:0xf bank_mask:0xf" \
      : "=v"(DST) : "v"(SRC), "v"(COEF))
#define ROT_FMAC(ACC, SRC, COEF, ROT) \
  asm("v_fmac_f32_dpp %0, %1, %2 row_ror:" #ROT " row_mask:0xf bank_mask:0xf" \
      : "+v"(ACC) : "v"(SRC), "v"(COEF))

// matvec over 16-lane rows: 8 indep chains of depth 2, then 3-level tree
#define STEP16(EC) { \
  float a0 = EC[0] * A, a1, a2, a3, a4, a5, a6, a7; \
  ROT_MUL(a1, A, EC[1], 1); ROT_MUL(a2, A, EC[2], 2); ROT_MUL(a3, A, EC[3], 3); \
  ROT_MUL(a4, A, EC[4], 4); ROT_MUL(a5, A, EC[5], 5); ROT_MUL(a6, A, EC[6], 6); \
  ROT_MUL(a7, A, EC[7], 7); \
  ROT_FMAC(a0, A, EC[8], 8);   ROT_FMAC(a1, A, EC[9], 9); \
  ROT_FMAC(a2, A, EC[10], 10); ROT_FMAC(a3, A, EC[11], 11); \
  ROT_FMAC(a4, A, EC[12], 12); ROT_FMAC(a5, A, EC[13], 13); \
  ROT_FMAC(a6, A, EC[14], 14); ROT_FMAC(a7, A, EC[15], 15); \
  part = ((a0 + a1) + (a2 + a3)) + ((a4 + a5) + (a6 + a7)); }

// ======================= FCC chain ======================================

#define FCC_RENORM() { \
  unsigned uu = (unsigned)__builtin_amdgcn_readfirstlane((int)__float_as_uint(A)); \
  int ex = (int)((uu >> 23) & 255) - 127; \
  A = ldexpf(A, -ex); Kt += ex; }

#define FCC_CONSUME8(PB) { \
  float eb[8]; \
  _Pragma("unroll") for (int q = 0; q < 8; ++q) eb[q] = sE[PB][q][(q & 1) ? lam1 : lam2]; \
  { float part; STEP16(Ec1); A = eb[0] * xsum16(part); } \
  { float part; STEP16(Ec2); A = eb[1] * xsum32(part); } \
  { float part; STEP16(Ec1); A = eb[2] * xsum16(part); } \
  { float part; STEP16(Ec2); A = eb[3] * xsum32(part); } \
  { float part; STEP16(Ec1); A = eb[4] * xsum16(part); } \
  { float part; STEP16(Ec2); A = eb[5] * xsum32(part); } \
  { float part; STEP16(Ec1); A = eb[6] * xsum16(part); } \
  { float part; STEP16(Ec2); A = eb[7] * xsum32(part); } \
  FCC_RENORM(); }

#define FCC_TAIL8(PB, CNT) { \
  float eb[8]; \
  _Pragma("unroll") for (int q = 0; q < 8; ++q) eb[q] = sE[PB][q][(q & 1) ? lam1 : lam2]; \
  _Pragma("unroll") for (int q = 0; q < 8; ++q) { \
    if (q >= (CNT)) break; \
    if ((q & 1) == 0) { float part; STEP16(Ec1); A = eb[q] * xsum16(part); } \
    else              { float part; STEP16(Ec2); A = eb[q] * xsum32(part); } } }

// backward (transpose): consumes rows 7..0; emission multiplies BEFORE matvec
#define FCC_BWDCON8(PB) { \
  float eb[8]; \
  _Pragma("unroll") for (int q = 0; q < 8; ++q) eb[q] = sE[PB][q][(q & 1) ? lam1 : lam2]; \
  { A *= eb[7]; float part; STEP16(E1T); A = xsum16(part); } \
  { A *= eb[6]; float part; STEP16(E2T); A = xsum32(part); } \
  { A *= eb[5]; float part; STEP16(E1T); A = xsum16(part); } \
  { A *= eb[4]; float part; STEP16(E2T); A = xsum32(part); } \
  { A *= eb[3]; float part; STEP16(E1T); A = xsum16(part); } \
  { A *= eb[2]; float part; STEP16(E2T); A = xsum32(part); } \
  { A *= eb[1]; float part; STEP16(E1T); A = xsum16(part); } \
  { A *= eb[0]; float part; STEP16(E2T); A = xsum32(part); } \
  FCC_RENORM(); }

// ======================= FAC chain (E-only staging, 16-step phases) =====
// sFE[.][r][l] = {E[tg0],E[tg1],E[tg2],E[tg3]} gathered for lane l at row r.
// Premultiplies (E*stay, E*move) are done IN-CHAIN but off the dependent
// path (dep path stays mul->fmaf from A-regs).

#define FAC_BOUNDARY_S() { \
  float maxA = fmaxf(fmaxf(A0, A1), fmaxf(A2, A3)); \
  if (maxA > 0.f) { \
    int ex = (int)((__float_as_uint(maxA) >> 23) & 255) - 127; \
    A0 = ldexpf(A0, -ex); A1 = ldexpf(A1, -ex); \
    A2 = ldexpf(A2, -ex); A3 = ldexpf(A3, -ex); \
    m += (float)ex; \
  } \
  float mp = dpp_f<0x138>(m, NEGF); m = (m == NEGF) ? mp : m; \
  mp = dpp_f<0x138>(m, NEGF);       m = (m == NEGF) ? mp : m; \
  mp = dpp_f<0x138>(m, NEGF); \
  float dlt = fminf(mp - m, 50.0f); \
  Sin = exp2f(dlt); }

#define FSTEPE(R) { \
  float c0 = Er[R].x * ST[0], c1 = Er[R].y * ST[1]; \
  float c2 = Er[R].z * ST[2], c3 = Er[R].w * ST[3]; \
  float v0 = Er[R].x * CM[0], v1 = Er[R].y * CM[1]; \
  float v2 = Er[R].z * CM[2], v3 = Er[R].w * CM[3]; \
  float ap = dpp_f<0x138>(A3, 0.f); /* wave_shr:1 */ \
  float n0 = fmaf(v0 * Sin, ap, c0 * A0); \
  float n1 = fmaf(v1, A0, c1 * A1); \
  float n2 = fmaf(v2, A1, c2 * A2); \
  float n3 = fmaf(v3, A2, c3 * A3); \
  A0 = n0; A1 = n1; A2 = n2; A3 = n3; }

#define FACF_CON16(PB) { \
  float4 Er[16]; \
  _Pragma("unroll") for (int r = 0; r < 16; ++r) Er[r] = sFE[PB][r][l]; \
  FSTEPE(0); FSTEPE(1); FSTEPE(2); FSTEPE(3); \
  FSTEPE(4); FSTEPE(5); FSTEPE(6); FSTEPE(7); \
  FAC_BOUNDARY_S(); \
  FSTEPE(8); FSTEPE(9); FSTEPE(10); FSTEPE(11); \
  FSTEPE(12); FSTEPE(13); FSTEPE(14); FSTEPE(15); \
  FAC_BOUNDARY_S(); }

#define FACF_TAIL16(PB, CNT) { \
  float4 Er[16]; \
  _Pragma("unroll") for (int r = 0; r < 16; ++r) Er[r] = sFE[PB][r][l]; \
  _Pragma("unroll") for (int r = 0; r < 16; ++r) { \
    if (r >= (CNT)) break; \
    FSTEPE(r); \
    if (r == 7) { FAC_BOUNDARY_S(); } } }

#define FACB_BOUNDARY_S() { \
  float maxA = fmaxf(fmaxf(A0, A1), fmaxf(A2, A3)); \
  if (maxA > 0.f) { \
    int ex = (int)((__float_as_uint(maxA) >> 23) & 255) - 127; \
    A0 = ldexpf(A0, -ex); A1 = ldexpf(A1, -ex); \
    A2 = ldexpf(A2, -ex); A3 = ldexpf(A3, -ex); \
    m += (float)ex; \
  } \
  float mp = dpp_f<0x130>(m, NEGF); m = (m == NEGF) ? mp : m; \
  mp = dpp_f<0x130>(m, NEGF);       m = (m == NEGF) ? mp : m; \
  mp = dpp_f<0x130>(m, NEGF); \
  float dlt = fminf(mp - m, 50.0f); \
  Sb = exp2f(dlt); }

#define FBSTEPE(R) { \
  float c0 = Er[R].x * ST[0], c1 = Er[R].y * ST[1]; \
  float c2 = Er[R].z * ST[2], c3 = Er[R].w * ST[3]; \
  float w0 = Er[R].y * CM[0], w1 = Er[R].z * CM[1], w2 = Er[R].w * CM[2]; \
  float en3 = dpp_f<0x130>(Er[R].x, 0.f); /* wave_shl:1 */ \
  float w3 = en3 * CM[3]; \
  float an = dpp_f<0x130>(A0, 0.f); \
  float n0 = fmaf(w0, A1, c0 * A0); \
  float n1 = fmaf(w1, A2, c1 * A1); \
  float n2 = fmaf(w2, A3, c2 * A2); \
  float n3 = fmaf(w3 * Sb, an, c3 * A3); \
  A0 = n0; A1 = n1; A2 = n2; A3 = n3; }

#define FACB_CON16(PB) { \
  float4 Er[16]; \
  _Pragma("unroll") for (int r = 0; r < 16; ++r) Er[r] = sFE[PB][r][l]; \
  FBSTEPE(15); FBSTEPE(14); FBSTEPE(13); FBSTEPE(12); \
  FBSTEPE(11); FBSTEPE(10); FBSTEPE(9);  FBSTEPE(8); \
  FACB_BOUNDARY_S(); \
  FBSTEPE(7);  FBSTEPE(6);  FBSTEPE(5);  FBSTEPE(4); \
  FBSTEPE(3);  FBSTEPE(2);  FBSTEPE(1);  FBSTEPE(0); \
  FACB_BOUNDARY_S(); }

// ======================= staging loads ==================================

// FCC (8-row phases)
#define HLDF(Q, K) ({ \
  int tt_ = t0 + 8 * (Q) + 2 * (K) + rowoff; \
  tt_ = tt_ > lenm1 ? lenm1 : tt_; \
  gpl[(size_t)tt_ * STRIDE_T]; })
#define HLDB(Q, K) ({ \
  int tt_ = thi - 8 * (Q) - 7 + 2 * (K) + rowoff; \
  tt_ = tt_ < 0 ? 0 : (tt_ > lenm1 ? lenm1 : tt_); \
  gpl[(size_t)tt_ * STRIDE_T]; })
#define HLD2(Q, K) ( isfwd ? HLDF(Q, K) : HLDB(Q, K) )

// FAC (16-row phases)
#define FHLD(Q, K) ({ \
  int tt_ = (isfwd ? (t0 + 16 * (Q)) : (thi - 16 * (Q) - 15)) + 2 * (K) + rowoff; \
  tt_ = tt_ < 0 ? 0 : (tt_ > lenm1 ? lenm1 : tt_); \
  gpl[(size_t)tt_ * STRIDE_T]; })

#define PROD_FCC(PB, KK, RV) { sE[PB][2 * (KK) + rowoff][lam1] = __expf(RV); }

// FAC gather-only produce: one loaded value covers 2 rows (lane halves)
#define PRODE(PB, KK, RV) { \
  float e_ = __expf(RV); \
  float4 E0_, E1_; \
  E0_.x = bperm(adA[0], e_); E0_.y = bperm(adA[1], e_); \
  E0_.z = bperm(adA[2], e_); E0_.w = bperm(adA[3], e_); \
  E1_.x = bperm(adB[0], e_); E1_.y = bperm(adB[1], e_); \
  E1_.z = bperm(adB[2], e_); E1_.w = bperm(adB[3], e_); \
  sFE[PB][2 * (KK)][l]     = E0_; \
  sFE[PB][2 * (KK) + 1][l] = E1_; }

// ======================= main kernel ====================================
// grid: [0, 2*64)        = FAC halves (chain + 2 helpers)  -- dispatched first
//       [2*64, 16*64)    = FCC chunk scans (chain + 1 helper + 1 dummy)

extern "C" __global__ __launch_bounds__(192, 1)
void asg_main(const float* __restrict__ trans, const float* __restrict__ inputs,
              const int* __restrict__ targets, const int* __restrict__ ilen,
              const int* __restrict__ tlen, float* __restrict__ ws) {
  const int tid = (int)threadIdx.x;
  const int w = tid >> 6;
  const int l = tid & 63;
  const int lam1 = l & 31;
  const int lam2 = (l & 15) | ((l >> 5) << 4);
  const int rowoff = l >> 5;
  const int bid = (int)blockIdx.x;

  __shared__ float  sE[2][8][32];    // FCC emission staging (2 KB)
  __shared__ float4 sFE[2][16][64];  // FAC gathered-E staging (32 KB)

  if (bid >= 2 * TB) {
    // ================= FCC chunk scans ================================
    const int cid = bid - 2 * TB;
    const int s = cid >> 6;          // scan id 0..13
    const int b = cid & 63;
    const int len = ilen[b];
    const int lenm1 = len - 1;
    const int Lsteps = lenm1;
    int L = ((Lsteps / NCH) + 4) & ~7;           // balanced chunk length
    if ((NCH - 1) * L > Lsteps) L = (Lsteps / NCH) & ~7;
    const int n0 = Lsteps - (NCH - 1) * L;       // chunk0 length (has tail)

    bool isfwd; int t0 = 1, thi = lenm1, nsteps, outslot;
    if (s == 0)      { isfwd = true;  t0 = 1; nsteps = n0; outslot = 0; }
    else if (s == 1) { isfwd = false; thi = lenm1; nsteps = L; outslot = 1; }
    else {
      const int j = s >> 1;                      // 1..6
      if ((s & 1) == 0) { isfwd = true;  t0 = n0 + (j - 1) * L + 1; nsteps = L; outslot = 2 * j; }
      else              { isfwd = false; thi = n0 + j * L;          nsteps = L; outslot = 2 * j + 1; }
    }
    const int nph = (nsteps + 7) >> 3;
    const float* gpl = inputs + (size_t)b * LL + lam1;
    float* P = ws + (size_t)b * WSB + OF_FCC + outslot * 33;

    if (w == 0) {
      __builtin_amdgcn_s_setprio(1);
      if (isfwd) {
        float Ec1[16], Ec2[16];
        Ec1[0] = __expf(trans[lam2 * LL + lam1]);
        Ec2[0] = __expf(trans[lam1 * LL + lam2]);
        Calib<1>::run(trans, lam1, lam2, Ec1);
        Calib<1>::run(trans, lam2, lam1, Ec2);
        float A = (s == 0) ? __expf(inputs[(size_t)b * LL + lam1]) : 1.f;
        int Kt = 0;
        for (int p = 0; p < nph; p += 2) {
          BARX();
          { const int rem = nsteps - 8 * p;
            if (rem >= 8) { FCC_CONSUME8(0); } else { FCC_TAIL8(0, rem); } }
          BARX();
          if (p + 1 < nph) {
            const int rem = nsteps - 8 * (p + 1);
            if (rem >= 8) { FCC_CONSUME8(1); } else { FCC_TAIL8(1, rem); }
          }
        }
        const int par = nsteps & 1;
        const int idx = par ? lam2 : lam1;
        const bool wr = par ? ((l & 16) == 0) : (l < 32);
        if (wr) P[idx] = A;
        if (l == 0) P[32] = (float)Kt;
      } else {
        float E1T[16], E2T[16];
        E1T[0] = __expf(trans[lam1 * LL + lam2]);
        E2T[0] = __expf(trans[lam2 * LL + lam1]);
        CalibT<1>::run(trans, lam1, lam2, E1T);
        CalibT<1>::run(trans, lam2, lam1, E2T);
        float A = 1.f;
        int Kt = 0;
        for (int p = 0; p < nph; p += 2) {
          BARX();
          FCC_BWDCON8(0);
          BARX();
          if (p + 1 < nph) { FCC_BWDCON8(1); }
        }
        if (l < 32) P[lam1] = A;      // L mult of 8 -> lam1 layout
        if (l == 0) P[32] = (float)Kt;
      }
    } else if (w == 1) {
      // single helper stages all 4 pairs, 3-deep prefetch
      float R1[4], R2[4], R3[4];
      #pragma unroll
      for (int k = 0; k < 4; ++k) R1[k] = HLD2(0, k);
      #pragma unroll
      for (int k = 0; k < 4; ++k) R2[k] = HLD2(1, k);
      #pragma unroll
      for (int k = 0; k < 4; ++k) R3[k] = HLD2(2, k);
      #pragma unroll
      for (int k = 0; k < 4; ++k) PROD_FCC(0, k, R1[k]);
      #pragma unroll
      for (int k = 0; k < 4; ++k) { R1[k] = R2[k]; R2[k] = R3[k]; R3[k] = HLD2(3, k); }
      for (int p = 0; p < nph; p += 2) {
        BARX();
        if (p + 1 < nph) {
          float N[4];
          #pragma unroll
          for (int k = 0; k < 4; ++k) N[k] = HLD2(p + 4, k);
          #pragma unroll
          for (int k = 0; k < 4; ++k) PROD_FCC(1, k, R1[k]);
          #pragma unroll
          for (int k = 0; k < 4; ++k) { R1[k] = R2[k]; R2[k] = R3[k]; R3[k] = N[k]; }
        }
        BARX();
        if (p + 2 < nph) {
          float N[4];
          #pragma unroll
          for (int k = 0; k < 4; ++k) N[k] = HLD2(p + 5, k);
          #pragma unroll
          for (int k = 0; k < 4; ++k) PROD_FCC(0, k, R1[k]);
          #pragma unroll
          for (int k = 0; k < 4; ++k) { R1[k] = R2[k]; R2[k] = R3[k]; R3[k] = N[k]; }
        }
      }
    } else {
      // dummy: barrier participation only
      const int I = (nph + 1) >> 1;
      for (int i = 0; i < I; ++i) { BARX(); BARX(); }
    }
    return;
  }

  // ================= FAC halves (dispatched first) =====================
  const int role = bid >> 6;   // 0 fwd, 1 bwd
  const int b    = bid & 63;

  const int len = ilen[b];
  const int lenm1 = len - 1;
  const int Lsteps = lenm1;
  const int nbf = (Lsteps / 2) & ~15;    // bwd steps (mult of 16 -> no tail)
  const int nff = Lsteps - nbf;          // fwd steps (tail ok)
  const bool isfwd = (role == 0);
  const int t0 = 1, thi = lenm1;
  const int nsteps = isfwd ? nff : nbf;
  const int nph = (nsteps + 15) >> 4;

  const float* gpl = inputs + (size_t)b * LL + lam1;
  float* P = ws + (size_t)b * WSB;

  if (w == 0) {
    // ---- chain wave: reads gathered E, applies coefficients in-chain ----
    __builtin_amdgcn_s_setprio(1);
    int tg[4];
    #pragma unroll
    for (int q = 0; q < 4; ++q) tg[q] = targets[b * SS + 4 * l + q];
    float ST[4], CM[4];
    #pragma unroll
    for (int q = 0; q < 4; ++q) ST[q] = __expf(trans[tg[q] * LL + tg[q]]);

    if (isfwd) {
      CM[0] = (l == 0) ? 0.f : __expf(trans[tg[0] * LL + targets[b * SS + 4 * l - 1]]);
      #pragma unroll
      for (int q = 1; q < 4; ++q) CM[q] = __expf(trans[tg[q] * LL + tg[q - 1]]);

      float A0 = (l == 0) ? __expf(inputs[(size_t)b * LL + tg[0]]) : 0.f;
      float A1 = 0.f, A2 = 0.f, A3 = 0.f;
      float m  = (l == 0) ? 0.f : NEGF;
      float Sin;
      FAC_BOUNDARY_S();
      for (int p = 0; p < nph; p += 2) {
        BARX();
        { const int rem = nsteps - 16 * p;
          if (rem >= 16) { FACF_CON16(0); } else { FACF_TAIL16(0, rem); } }
        BARX();
        if (p + 1 < nph) {
          const int rem = nsteps - 16 * (p + 1);
          if (rem >= 16) { FACF_CON16(1); } else { FACF_TAIL16(1, rem); }
        }
      }
      P[OF_FACF + 4 * l + 0] = A0;
      P[OF_FACF + 4 * l + 1] = A1;
      P[OF_FACF + 4 * l + 2] = A2;
      P[OF_FACF + 4 * l + 3] = A3;
      P[OF_FACF + 256 + l]   = m;
    } else {
      CM[0] = __expf(trans[tg[1] * LL + tg[0]]);
      CM[1] = __expf(trans[tg[2] * LL + tg[1]]);
      CM[2] = __expf(trans[tg[3] * LL + tg[2]]);
      int tgn3 = (l < 63) ? targets[b * SS + 4 * l + 4] : 0;
      CM[3] = (l < 63) ? __expf(trans[tgn3 * LL + tg[3]]) : 0.f;

      const int tl = tlen[b];
      const int fs = tl - 1;
      float A0 = (4 * l + 0 == fs) ? 1.f : 0.f;
      float A1 = (4 * l + 1 == fs) ? 1.f : 0.f;
      float A2 = (4 * l + 2 == fs) ? 1.f : 0.f;
      float A3 = (4 * l + 3 == fs) ? 1.f : 0.f;
      float m  = (l == (fs >> 2)) ? 0.f : NEGF;
      float Sb;
      FACB_BOUNDARY_S();
      for (int p = 0; p < nph; p += 2) {
        BARX();
        FACB_CON16(0);
        BARX();
        if (p + 1 < nph) { FACB_CON16(1); }
      }
      P[OF_FACB + 4 * l + 0] = A0;
      P[OF_FACB + 4 * l + 1] = A1;
      P[OF_FACB + 4 * l + 2] = A2;
      P[OF_FACB + 4 * l + 3] = A3;
      P[OF_FACB + 256 + l]   = m;
    }
  } else {
    // ---- 2 helper waves: gather-only staging, 4 pairs each, 3-deep ------
    const int kh = 4 * (w - 1);          // pair indices kh..kh+3
    int adA[4], adB[4];
    #pragma unroll
    for (int j = 0; j < 4; ++j) {
      int tg = targets[b * SS + 4 * l + j];
      adA[j] = tg * 4; adB[j] = adA[j] + 128;
    }
    float R1[4], R2[4], R3[4];
    #pragma unroll
    for (int k = 0; k < 4; ++k) R1[k] = FHLD(0, kh + k);
    #pragma unroll
    for (int k = 0; k < 4; ++k) R2[k] = FHLD(1, kh + k);
    #pragma unroll
    for (int k = 0; k < 4; ++k) R3[k] = FHLD(2, kh + k);
    #pragma unroll
    for (int k = 0; k < 4; ++k) PRODE(0, kh + k, R1[k]);
    #pragma unroll
    for (int k = 0; k < 4; ++k) { R1[k] = R2[k]; R2[k] = R3[k]; R3[k] = FHLD(3, kh + k); }

    for (int p = 0; p < nph; p += 2) {
      BARX();
      if (p + 1 < nph) {
        float N[4];
        #pragma unroll
        for (int k = 0; k < 4; ++k) N[k] = FHLD(p + 4, kh + k);
        #pragma unroll
        for (int k = 0; k < 4; ++k) PRODE(1, kh + k, R1[k]);
        #pragma unroll
        for (int k = 0; k < 4; ++k) { R1[k] = R2[k]; R2[k] = R3[k]; R3[k] = N[k]; }
      }
      BARX();
      if (p + 2 < nph) {
        float N[4];
        #pragma unroll
        for (int k = 0; k < 4; ++k) N[k] = FHLD(p + 5, kh + k);
        #pragma unroll
        for (int k = 0; k < 4; ++k) PRODE(0, kh + k, R1[k]);
        #pragma unroll
        for (int k = 0; k < 4; ++k) { R1[k] = R2[k]; R2[k] = R3[k]; R3[k] = N[k]; }
      }
    }
  }
}

// ======================= combine ========================================

extern "C" __global__ __launch_bounds__(1024)
void asg_combine(const float* __restrict__ ws, float* __restrict__ out) {
  __shared__ float sd[TB];
  const int tid = (int)threadIdx.x;
  const int w = tid >> 6, l = tid & 63;

  for (int k = 0; k < 4; ++k) {
    const int b = w * 4 + k;
    const float* P = ws + (size_t)b * WSB;

    // ---- FCC: telescoped rank-1 chunk products ----
    float acc = 0.f;
    float Ksum = P[OF_FCC + 0 * 33 + 32];           // Ka
    #pragma unroll
    for (int j = 0; j <= NI; ++j) {
      const int qs = (j == NI) ? 1 : (2 * j + 3);   // q_{j+1}, last = c
      const int ps = (j == 0) ? 0 : (2 * j);        // p_j, first = a
      float qv = (l < 32) ? P[OF_FCC + qs * 33 + l] : 0.f;
      float pv = (l < 32) ? P[OF_FCC + ps * 33 + l] : 0.f;
      float d = qv * pv;
      #pragma unroll
      for (int mm = 1; mm < 64; mm <<= 1) d += __shfl_xor(d, mm);
      acc += __logf(d);
      Ksum += P[OF_FCC + qs * 33 + 32];             // Kq (or Kc)
    }
    #pragma unroll
    for (int j = 1; j <= NI; ++j) {
      float pv = (l < 32) ? P[OF_FCC + 2 * j * 33 + l] : 0.f;
      #pragma unroll
      for (int mm = 1; mm < 64; mm <<= 1) pv += __shfl_xor(pv, mm);
      acc -= __logf(pv);
    }
    float fcc = acc + Ksum * LN2F;

    // ---- FAC: score = sum_s alpha[s] * beta[s] ----
    float pa = P[OF_FACF + 4 * l + 0] * P[OF_FACB + 4 * l + 0]
             + P[OF_FACF + 4 * l + 1] * P[OF_FACB + 4 * l + 1]
             + P[OF_FACF + 4 * l + 2] * P[OF_FACB + 4 * l + 2]
             + P[OF_FACF + 4 * l + 3] * P[OF_FACB + 4 * l + 3];
    float sc = P[OF_FACF + 256 + l] + P[OF_FACB + 256 + l];
    float Ms = sc;
    #pragma unroll
    for (int mm = 1; mm < 64; mm <<= 1) Ms = fmaxf(Ms, __shfl_xor(Ms, mm));
    float pp = pa * exp2f(sc - Ms);
    #pragma unroll
    for (int mm = 1; mm < 64; mm <<= 1) pp += __shfl_xor(pp, mm);
    float fac = __logf(pp) + Ms * LN2F;

    if (l == 0) sd[b] = fcc - fac;
  }
  __syncthreads();
  if (tid < TB) {
    float d = sd[tid];
    #pragma unroll
    for (int mm = 1; mm < 64; mm <<= 1) d += __shfl_xor(d, mm);
    if (tid == 0) out[0] = d * (1.0f / TB);
  }
}

// ======================= launcher =======================================

extern "C" void kernel_launch(void* const* d_in, const int* in_sizes, int n_in,
                              void* d_out, int out_size, void* d_ws, size_t ws_size,
                              hipStream_t stream) {
  const float* trans   = (const float*)d_in[0];
  const float* inputs  = (const float*)d_in[1];
  const int*   targets = (const int*)d_in[2];
  const int*   ilen    = (const int*)d_in[3];
  const int*   tlen    = (const int*)d_in[4];
  float* out = (float*)d_out;
  float* ws  = (float*)d_ws;

  // 2*64 FAC halves first, then 14*64 FCC chunk scans; 3 waves per block
  asg_main<<<dim3((NSCAN + 2) * TB), dim3(192), 0, stream>>>(
      trans, inputs, targets, ilen, tlen, ws);
  asg_combine<<<dim3(1), dim3(1024), 0, stream>>>(ws, out);
}